// Round 5
// baseline (23008.372 us; speedup 1.0000x reference)
//
#include <hip/hip_runtime.h>

// ULSTM layer: S=1024, B=32, IN=1024, H=1024
//  R7 = R6 (tag-in-data exchange) with the workspace overflow fixed.
//  R6 placed hx/vx/bars PAST the proven workspace budget (356,675,584 B) ->
//  suspected OOB fault -> container death. Now the exchange buffers alias the
//  W0p region (only live during gemm_in, which finishes before ulstm_rec),
//  and the bar/exchange memset runs stream-ordered AFTER gemm_in.
//
//  Exchange design (R6): h/v published as 16B chunks {7 bf16 + u16 step tag}
//  via single global_store_dwordx4 sc0 sc1 (tag+data arrive atomically at the
//  IF$). Consumers poll chunks DIRECTLY until tag==t+1: producer->consumer =
//  ~1 coherent RTT, no drain, no flag hop. Two LAGGED anti-overwrite barriers
//  (arrive after reads, waited on one phase later, overlapped with gemm work)
//  keep parity buffers safe. Buffers zeroed each replay (tag 0 never matches).

typedef unsigned short u16;
typedef __attribute__((ext_vector_type(4))) float f32x4;
typedef __attribute__((ext_vector_type(8))) short s16x8;     // 8 bf16 (MFMA A/B frag)
typedef __attribute__((ext_vector_type(8))) unsigned short u16x8;

#define SEQ   1024
#define BATCH 32
#define HDIM  1024
#define GBLK  64          // persistent blocks; each owns 16 hidden cols

__device__ __forceinline__ u16 f2bf(float f) {
    unsigned u = __builtin_bit_cast(unsigned, f);
    return (u16)((u + 0x7FFFu + ((u >> 16) & 1u)) >> 16);   // RNE
}
__device__ __forceinline__ float bf2f(u16 h) {
    return __builtin_bit_cast(float, (unsigned)h << 16);
}

__device__ __forceinline__ void vmwait0() {
    asm volatile("s_waitcnt vmcnt(0)" ::: "memory");
    __builtin_amdgcn_sched_barrier(0);       // rule #18: pin uses after the wait
}
// coherent 16B store (single fabric transaction; bypasses L1/L2 -> IF$)
__device__ __forceinline__ void gstore_cc16(u16* p, u16x8 d) {
    asm volatile("global_store_dwordx4 %0, %1, off sc0 sc1" :: "v"(p), "v"(d) : "memory");
}

// ---------------------------------------------------------------- prep kernels
// permuted column p: g = p/80, r = p%80, gate = r>>4 (0..4 = i,o,z,f,u), j = r&15
// hidden index n = 16g + j; original 5H col = gate<4 ? gate*H+n : 4H+n
__global__ void prep_w0(const float* __restrict__ W, const float* __restrict__ b_ux,
                        const float* __restrict__ b_h, const float* __restrict__ b_um,
                        u16* __restrict__ W0p, float* __restrict__ biasp) {
    int p = blockIdx.x;                       // 5120
    int g = p / 80, r = p % 80, gate = r >> 4, j = r & 15;
    int n = 16 * g + j;
    int c = (gate < 4) ? gate * 1024 + n : 4096 + n;
    for (int k = threadIdx.x; k < 1024; k += 256)
        W0p[(long)p * 1024 + k] = f2bf(W[(long)k * 5120 + c]);
    if (threadIdx.x == 0)
        biasp[p] = b_ux[c] + ((gate < 4) ? b_h[gate * 1024 + n] : b_um[n]);
}

__global__ void prep_w1(const float* __restrict__ W, u16* __restrict__ W1p) {
    int qq = blockIdx.x;                      // 4096
    int g = qq >> 6, r = qq & 63, gate = r >> 4, j = r & 15;
    int n = 16 * g + j;
    int c = gate * 1024 + n;
    for (int k = threadIdx.x; k < 1024; k += 256)
        W1p[(long)qq * 1024 + k] = f2bf(W[(long)k * 4096 + c]);
}

__global__ void prep_w2(const float* __restrict__ W, u16* __restrict__ W2p) {
    int n = blockIdx.x;                       // 1024
    for (int k = threadIdx.x; k < 1024; k += 256)
        W2p[(long)n * 1024 + k] = f2bf(W[(long)k * 1024 + n]);
}

// ---------------------------------------------------------- input projection
__global__ void __launch_bounds__(256) gemm_in(const float* __restrict__ X,
                                               const u16* __restrict__ W0p,
                                               const float* __restrict__ biasp,
                                               u16* __restrict__ Yp) {
    __shared__ u16 As[128 * 40];
    __shared__ u16 Bs[64 * 40];
    const int tid = threadIdx.x, lane = tid & 63, w = tid >> 6;
    const int m = lane & 15, q = lane >> 4;
    const int m0 = blockIdx.y * 128, n0 = blockIdx.x * 64;

    f32x4 acc[2][4];
#pragma unroll
    for (int a = 0; a < 2; ++a)
#pragma unroll
        for (int b = 0; b < 4; ++b) acc[a][b] = (f32x4){0.f, 0.f, 0.f, 0.f};

    const int ar = tid >> 1, as = (tid & 1) * 16;
    const int br = tid >> 2, bs = (tid & 3) * 8;

    for (int k0 = 0; k0 < 1024; k0 += 32) {
        const float* xp = X + (long)(m0 + ar) * 1024 + k0 + as;
        float4 x0 = *(const float4*)(xp);
        float4 x1 = *(const float4*)(xp + 4);
        float4 x2 = *(const float4*)(xp + 8);
        float4 x3 = *(const float4*)(xp + 12);
        u16x8 pa, pb;
        pa[0]=f2bf(x0.x); pa[1]=f2bf(x0.y); pa[2]=f2bf(x0.z); pa[3]=f2bf(x0.w);
        pa[4]=f2bf(x1.x); pa[5]=f2bf(x1.y); pa[6]=f2bf(x1.z); pa[7]=f2bf(x1.w);
        pb[0]=f2bf(x2.x); pb[1]=f2bf(x2.y); pb[2]=f2bf(x2.z); pb[3]=f2bf(x2.w);
        pb[4]=f2bf(x3.x); pb[5]=f2bf(x3.y); pb[6]=f2bf(x3.z); pb[7]=f2bf(x3.w);
        u16x8 bv = *(const u16x8*)(W0p + (long)(n0 + br) * 1024 + k0 + bs);

        *(u16x8*)&As[ar * 40 + as]     = pa;
        *(u16x8*)&As[ar * 40 + as + 8] = pb;
        *(u16x8*)&Bs[br * 40 + bs]     = bv;
        __syncthreads();

        s16x8 a0 = *(const s16x8*)&As[(w * 32 + m) * 40 + q * 8];
        s16x8 a1 = *(const s16x8*)&As[(w * 32 + 16 + m) * 40 + q * 8];
#pragma unroll
        for (int nt = 0; nt < 4; ++nt) {
            s16x8 b = *(const s16x8*)&Bs[(nt * 16 + m) * 40 + q * 8];
            acc[0][nt] = __builtin_amdgcn_mfma_f32_16x16x32_bf16(a0, b, acc[0][nt], 0, 0, 0);
            acc[1][nt] = __builtin_amdgcn_mfma_f32_16x16x32_bf16(a1, b, acc[1][nt], 0, 0, 0);
        }
        __syncthreads();
    }
#pragma unroll
    for (int mt = 0; mt < 2; ++mt)
#pragma unroll
        for (int nt = 0; nt < 4; ++nt) {
            int p = n0 + nt * 16 + m;
            int gg = p / 80, rr = p - gg * 80;
            float bias = biasp[p];
#pragma unroll
            for (int r = 0; r < 4; ++r) {
                int row = m0 + w * 32 + mt * 16 + q * 4 + r;
                int s = row >> 5, b = row & 31;
                Yp[(((long)gg * 1024 + s) * 32 + b) * 80 + rr] = f2bf(acc[mt][nt][r] + bias);
            }
        }
}

// -------------------------------------------------------- chunk poll + unpack
// Exchange layout: [parity][2048 grp = row*64+g][3 chunks][8 u16], 48B/grp.
// Chunk = {7 bf16 payload, u16 tag}. Thread owns grps [tid*8, tid*8+8) ->
// 24 chunks, contiguous 384B at lanebase; chunk i at byte offset i*16.
#define ISSUE1(i, ofs)                                                        \
    if (!((valid >> i) & 1))                                                  \
        asm volatile("global_load_dwordx4 %0, %1, off offset:" ofs " sc0 sc1" \
                     : "=&v"(ch[i]) : "v"(lanebase));

__device__ __forceinline__ void poll_unpack(const u16* lanebase, unsigned valid,
                                            u16 want, u16* stage_, int tid) {
    u16x8 ch[24];
    int rounds = 0;
    while (valid != 0xFFFFFFu) {
        if (rounds++) __builtin_amdgcn_s_sleep(1);
        ISSUE1(0, "0")   ISSUE1(1, "16")   ISSUE1(2, "32")   ISSUE1(3, "48")
        ISSUE1(4, "64")  ISSUE1(5, "80")   ISSUE1(6, "96")   ISSUE1(7, "112")
        ISSUE1(8, "128") ISSUE1(9, "144")  ISSUE1(10, "160") ISSUE1(11, "176")
        ISSUE1(12, "192") ISSUE1(13, "208") ISSUE1(14, "224") ISSUE1(15, "240")
        ISSUE1(16, "256") ISSUE1(17, "272") ISSUE1(18, "288") ISSUE1(19, "304")
        ISSUE1(20, "320") ISSUE1(21, "336") ISSUE1(22, "352") ISSUE1(23, "368")
        vmwait0();
#pragma unroll
        for (int i = 0; i < 24; ++i) {
            if (!((valid >> i) & 1) && ch[i][7] == want) {
                valid |= 1u << i;
                const int grp = tid * 8 + i / 3;
                const int row = grp >> 6, gg = grp & 63;
                const int col0 = gg * 16 + (i % 3) * 7;
                const int n = (i % 3 == 2) ? 2 : 7;
#pragma unroll
                for (int j = 0; j < 7; ++j)
                    if (j < n) stage_[row * 1032 + col0 + j] = ch[i][j];
            }
        }
    }
}

// ------------------------------------------------------------- recurrence
__global__ void __launch_bounds__(256, 1) ulstm_rec(const u16* __restrict__ W1p,
                                                    const u16* __restrict__ W2p,
                                                    const u16* __restrict__ Yp,
                                                    u16* hx, u16* vx,
                                                    float* __restrict__ out,
                                                    unsigned* bar1, unsigned* bar2) {
    __shared__ u16 stage[32 * 1032];        // h (phase A) / v (phase B)
    __shared__ u16 ys[2][2560];             // double-buffered Y slice (32x80)
    __shared__ float gl[4][32][17];         // i,o,v(=sig(z)*ct),f
    __shared__ float c_l[32][17], ct_l[32][17];
    __shared__ u16 h_l[32 * 17 + 8];        // bf16 h_t (padded for chunk reads)

    const int g = blockIdx.x, tid = threadIdx.x, lane = tid & 63, w = tid >> 6;
    const int m = lane & 15, q = lane >> 4;

    for (int i = tid; i < 512; i += 256) {
        int row = i >> 4, col = i & 15;
        c_l[row][col] = 0.f; ct_l[row][col] = 0.f;
    }
    for (int i = tid; i < 32 * 17 + 8; i += 256) h_l[i] = 0;

    if (tid < 96) {                         // publish h_0 = 0 chunks, tag 1
        int row = (tid * 171) >> 9, c = tid - 3 * row;
        u16x8 z = (u16x8){0, 0, 0, 0, 0, 0, 0, 0};
        z[7] = (u16)1;
        gstore_cc16(hx + (row * 64 + g) * 24 + c * 8, z);
    }
    {   // Y slice for t=0 (nontemporal: stream, don't pollute L2)
        const u16x8* src = (const u16x8*)(Yp + (long)g * 1024 * 2560);
        for (int i = tid; i < 320; i += 256)
            *(u16x8*)&ys[0][i * 8] = __builtin_nontemporal_load(&src[i]);
    }

    unsigned selfmask = 0;                  // own-block chunks: via LDS, not polled
#pragma unroll
    for (int i = 0; i < 24; ++i)
        if (((tid * 8 + i / 3) & 63) == g) selfmask |= 1u << i;
    const int prow = tid >> 3, pcp = (tid & 7) * 2;   // own-slice copy indices

    __syncthreads();                        // h_l zeros visible block-wide

    for (int t = 0; t < SEQ; ++t) {
        const u16* ysb = ys[t & 1];
        const u16 want = (u16)(t + 1);

        // Y prefetch first: overlaps under the chunk-poll RTT
        if (t + 1 < SEQ) {
            const u16x8* src = (const u16x8*)(Yp + ((long)g * 1024 + t + 1) * 2560);
            u16* dst = ys[(t + 1) & 1];
            for (int i = tid; i < 320; i += 256)
                *(u16x8*)&dst[i * 8] = __builtin_nontemporal_load(&src[i]);
        }

        // ---- phase A: stage h (own slice from LDS; remote via tag poll)
        stage[prow * 1032 + g * 16 + pcp]     = h_l[prow * 17 + pcp];
        stage[prow * 1032 + g * 16 + pcp + 1] = h_l[prow * 17 + pcp + 1];
        poll_unpack(hx + (t & 1) * 49152 + tid * 192, selfmask, want, stage, tid);
        __syncthreads();                              // sync#1: h staged

        unsigned fl = 0;
        if (w == 0) {
            if (tid == 0)                             // bar1 arrival: phase A reads done
                __hip_atomic_store(&bar1[g * 32], (unsigned)(t + 1),
                                   __ATOMIC_RELAXED, __HIP_MEMORY_SCOPE_AGENT);
            fl = __hip_atomic_load(&bar2[lane * 32], __ATOMIC_RELAXED,
                                   __HIP_MEMORY_SCOPE_AGENT);   // early issue; checked post-gemm1
        }

        // ---- gemm1: preact[32 x 16] for gate w (weights L2-resident)
        f32x4 acc0 = (f32x4){0.f,0.f,0.f,0.f}, acc1 = (f32x4){0.f,0.f,0.f,0.f};
        {
            const int brow = g * 64 + w * 16 + m;
            const u16* wp = W1p + (long)brow * 1024;
#pragma unroll 8
            for (int kc = 0; kc < 32; ++kc) {
                int k0 = kc * 32 + q * 8;
                s16x8 a0 = *(const s16x8*)&stage[m * 1032 + k0];
                s16x8 a1 = *(const s16x8*)&stage[(16 + m) * 1032 + k0];
                s16x8 b  = *(const s16x8*)&wp[k0];
                acc0 = __builtin_amdgcn_mfma_f32_16x16x32_bf16(a0, b, acc0, 0, 0, 0);
                acc1 = __builtin_amdgcn_mfma_f32_16x16x32_bf16(a1, b, acc1, 0, 0, 0);
            }
        }
#pragma unroll
        for (int r = 0; r < 4; ++r) {
            int row0 = q * 4 + r, row1 = row0 + 16;
            float p0 = acc0[r] + bf2f(ysb[row0 * 80 + w * 16 + m]);
            float p1 = acc1[r] + bf2f(ysb[row1 * 80 + w * 16 + m]);
            float g0 = 1.f / (1.f + __expf(-p0));
            float g1 = 1.f / (1.f + __expf(-p1));
            if (w == 2) {       // z-gate wave: store v = sigmoid(z) * tanh(c_prev)
                gl[2][row0][m] = g0 * ct_l[row0][m];
                gl[2][row1][m] = g1 * ct_l[row1][m];
            } else {
                gl[w][row0][m] = g0;
                gl[w][row1][m] = g1;
            }
        }
        // bar2 wait (gates vx[t&1] overwrite; lagged 2 steps -> normally instant)
        if (w == 0 && t >= 1) {
            while (__ballot((int)fl >= t - 1) != ~0ull) {
                __builtin_amdgcn_s_sleep(1);
                fl = __hip_atomic_load(&bar2[lane * 32], __ATOMIC_RELAXED,
                                       __HIP_MEMORY_SCOPE_AGENT);
            }
        }
        __syncthreads();                              // sync#2: gl ready, bar2 ok

        if (tid < 96) {                               // publish v chunks (tag t+1), fire-and-forget
            int row = (tid * 171) >> 9, c = tid - 3 * row;
            u16x8 pk;
#pragma unroll
            for (int j = 0; j < 7; ++j) pk[j] = f2bf(gl[2][row][c * 7 + j]);
            pk[7] = want;
            gstore_cc16(vx + (t & 1) * 49152 + (row * 64 + g) * 24 + c * 8, pk);
        }

        // ---- phase B: stage v (own slice from gl[2]; remote via tag poll)
        stage[prow * 1032 + g * 16 + pcp]     = f2bf(gl[2][prow][pcp]);
        stage[prow * 1032 + g * 16 + pcp + 1] = f2bf(gl[2][prow][pcp + 1]);
        poll_unpack(vx + (t & 1) * 49152 + tid * 192, selfmask, want, stage, tid);
        __syncthreads();                              // sync#3: v staged

        if (tid == 0)                                 // bar2 arrival: phase B reads done
            __hip_atomic_store(&bar2[g * 32], (unsigned)(t + 1),
                               __ATOMIC_RELAXED, __HIP_MEMORY_SCOPE_AGENT);
        unsigned fl2 = 0;
        if (w == 3)                                   // idle wave handles bar1 wait
            fl2 = __hip_atomic_load(&bar1[lane * 32], __ATOMIC_RELAXED,
                                    __HIP_MEMORY_SCOPE_AGENT);

        // ---- gemm2 + state update (waves 0,1)
        if (w < 2) {
            f32x4 acc = (f32x4){0.f,0.f,0.f,0.f};
            const u16* wp = W2p + (long)(g * 16 + m) * 1024;
#pragma unroll 8
            for (int kc = 0; kc < 32; ++kc) {
                int k0 = kc * 32 + q * 8;
                s16x8 a = *(const s16x8*)&stage[(w * 16 + m) * 1032 + k0];
                s16x8 b = *(const s16x8*)&wp[k0];
                acc = __builtin_amdgcn_mfma_f32_16x16x32_bf16(a, b, acc, 0, 0, 0);
            }
#pragma unroll
            for (int r = 0; r < 4; ++r) {
                int row = w * 16 + q * 4 + r;
                float up = acc[r] + bf2f(ysb[row * 80 + 64 + m]);
                float eu = __expf(2.f * up);
                float u = 1.f - 2.f / (eu + 1.f);           // tanh
                float iv = gl[0][row][m], ov = gl[1][row][m], fv = gl[3][row][m];
                float cv = c_l[row][m];
                float cn = iv * u + fv * cv;
                float ec = __expf(2.f * cn);
                float ctn = 1.f - 2.f / (ec + 1.f);
                float hn = ov * ctn;
                c_l[row][m] = cn;
                ct_l[row][m] = ctn;
                h_l[row * 17 + m] = f2bf(hn);
                __builtin_nontemporal_store(hn, &out[(long)(t * 32 + row) * 1024 + g * 16 + m]);
                if (t == SEQ - 1) {
                    out[33554432l + row * 1024 + g * 16 + m] = hn;          // h_n
                    out[33554432l + 32768 + row * 1024 + g * 16 + m] = cn;  // c_n
                }
            }
        }
        // bar1 wait (gates hx[(t+1)&1] overwrite; lagged -> overlaps gemm2)
        if (w == 3) {
            while (__ballot((int)fl2 >= t) != ~0ull) {
                __builtin_amdgcn_s_sleep(1);
                fl2 = __hip_atomic_load(&bar1[lane * 32], __ATOMIC_RELAXED,
                                        __HIP_MEMORY_SCOPE_AGENT);
            }
        }
        __syncthreads();                              // sync#4: h_l ready, bar1 ok

        if (t + 1 < SEQ && tid < 96) {                // publish h chunks (tag t+2)
            int row = (tid * 171) >> 9, c = tid - 3 * row;
            u16x8 pk;
#pragma unroll
            for (int j = 0; j < 7; ++j) pk[j] = h_l[row * 17 + c * 7 + j];
            pk[7] = (u16)(t + 2);
            gstore_cc16(hx + ((t + 1) & 1) * 49152 + (row * 64 + g) * 24 + c * 8, pk);
        }
    }
}

// ---------------------------------------------------------------------- host
extern "C" void kernel_launch(void* const* d_in, const int* in_sizes, int n_in,
                              void* d_out, int out_size, void* d_ws, size_t ws_size,
                              hipStream_t stream) {
    (void)in_sizes; (void)n_in; (void)out_size; (void)ws_size;
    const float* X  = (const float*)d_in[0];
    const float* W0 = (const float*)d_in[1];
    const float* b0 = (const float*)d_in[2];
    const float* W1 = (const float*)d_in[3];
    const float* b1 = (const float*)d_in[4];
    const float* W2 = (const float*)d_in[5];
    const float* b2 = (const float*)d_in[6];
    float* out = (float*)d_out;
    char* ws = (char*)d_ws;

    u16*   Yp    = (u16*)(ws);                      // 335,544,320 B
    u16*   W0p   = (u16*)(ws + 335544320l);         // 10,485,760 (live only in gemm_in)
    u16*   W1p   = (u16*)(ws + 346030080l);         // 8,388,608
    u16*   W2p   = (u16*)(ws + 354418688l);         // 2,097,152
    float* biasp = (float*)(ws + 356515840l);       // 20,480   (max ws offset: 356,536,320)

    // exchange buffers ALIAS the W0p region (dead after gemm_in):
    u16*   hx    = (u16*)(ws + 335544320l);         // 196,608 (2 x 2048 grp x 48B)
    u16*   vx    = (u16*)(ws + 335740928l);         // 196,608
    unsigned* bar1 = (unsigned*)(ws + 335937536l);  // 8,192 (64 x 128B)
    unsigned* bar2 = (unsigned*)(ws + 335945728l);  // 8,192 (ends 335,953,920 << W0p end)

    prep_w0<<<5120, 256, 0, stream>>>(W0, b0, b1, b2, W0p, biasp);
    prep_w1<<<4096, 256, 0, stream>>>(W1, W1p);
    prep_w2<<<1024, 256, 0, stream>>>(W2, W2p);
    gemm_in<<<dim3(80, 256), 256, 0, stream>>>(X, W0p, biasp, Yp);
    // zero hx+vx+bar1+bar2 AFTER gemm_in (stream-ordered; W0p now dead).
    // Zero tags never match want>=1 -> replay-safe by construction.
    hipMemsetAsync(hx, 0, 409600, stream);

    void* args[] = { (void*)&W1p, (void*)&W2p, (void*)&Yp,
                     (void*)&hx, (void*)&vx, (void*)&out,
                     (void*)&bar1, (void*)&bar2 };
    hipLaunchCooperativeKernel(reinterpret_cast<void*>(ulstm_rec),
                               dim3(GBLK), dim3(256), args, 0, stream);
}